// Round 7
// baseline (254.565 us; speedup 1.0000x reference)
//
#include <hip/hip_runtime.h>

// VectorQuantizer: z [32,2048,64] f32, codebook [1024,64] f32.
// out = concat( z_q [4194304], c_loss [1], cb_loss [1] ); c_loss==cb_loss (BETA=1).
//
// R7: R6's cooperative launch never ran (launch error unchecked -> all-zero out).
// Revert to plain stream launches: vq_prep + vq_main, with the loss finalize
// fused into vq_main via last-block-done counter (kills the 3rd launch).
// Compute design unchanged from R6: bf16 MFMA distance GEMM, A-fragments staged
// in LDS (no asm pins -> no R5 spill path), argmin via index-embedded v_min_f32,
// gather / z_q / losses exact fp32.

#define VQ_NTOK   65536
#define VQ_D      64
#define VQ_K      1024
#define VQ_NELEM  (VQ_NTOK * VQ_D)
#define VQ_NBLK   (VQ_NTOK / 64)

typedef short bf16x8 __attribute__((ext_vector_type(8)));
typedef float f32x4  __attribute__((ext_vector_type(4)));

#define WS_CSQ       0        // 1024 floats: ||c_k||^2
#define WS_LOSS      1024     // 1 float: loss accumulator
#define WS_CNT       1025     // 1 uint: blocks-done counter
#define WS_CBB_BYTES 8192     // byte offset: 128 KB fragment-ordered bf16 codebook

__device__ __forceinline__ short bf16rn(float x) {   // round-to-nearest-even
    unsigned u = __builtin_bit_cast(unsigned, x);
    u += 0x7fffu + ((u >> 16) & 1u);
    return (short)(u >> 16);
}

// grid 32 x 256: zero accumulators + csq + bf16 fragment-ordered codebook.
// Fragment order: (chunk c, half h, lane L) -> cb[c*16+(L&15)][h*32+(L>>4)*8 ..+8)
__global__ __launch_bounds__(256) void vq_prep(const float* __restrict__ cb,
                                               float* __restrict__ ws) {
    int t = blockIdx.x * 256 + threadIdx.x;   // 0..8191
    if (t == 0) { ws[WS_LOSS] = 0.0f; ((unsigned*)ws)[WS_CNT] = 0u; }
    if (t < VQ_K) {
        const float4* row = (const float4*)(cb + t * VQ_D);
        float s = 0.f;
        #pragma unroll
        for (int j = 0; j < 16; ++j) {
            float4 c = row[j];
            s += c.x * c.x + c.y * c.y + c.z * c.z + c.w * c.w;
        }
        ws[WS_CSQ + t] = s;
    }
    int c = t >> 7, h = (t >> 6) & 1, L = t & 63;
    int k  = c * 16 + (L & 15);
    int d0 = h * 32 + ((L >> 4) << 3);
    const float4* p = (const float4*)(cb + k * VQ_D + d0);
    float4 x0 = p[0], x1 = p[1];
    bf16x8 v;
    v[0] = bf16rn(x0.x); v[1] = bf16rn(x0.y); v[2] = bf16rn(x0.z); v[3] = bf16rn(x0.w);
    v[4] = bf16rn(x1.x); v[5] = bf16rn(x1.y); v[6] = bf16rn(x1.z); v[7] = bf16rn(x1.w);
    bf16x8* cbb = (bf16x8*)((char*)ws + WS_CBB_BYTES);
    cbb[(c * 2 + h) * 64 + L] = v;
}

__global__ __launch_bounds__(256, 4) void vq_main(
        const float* __restrict__ z, const float* __restrict__ cb,
        float* __restrict__ ws, float* __restrict__ out) {
    const int tid = threadIdx.x;
    const int bid = blockIdx.x;
    const int tokbase = bid << 6;
    const int tok = tid >> 2, part = tid & 3;   // token-quarter per thread

    __shared__ bf16x8 sA[512];          // 8 KB: 4 tiles x 2 halves x 64 lanes
    __shared__ float  s_bv[4][64];
    __shared__ int    s_bk[4][64];
    __shared__ float  s_loss[4];

    // Stage A-fragments into LDS (coalesced 64 B/thread z read, fragment-ordered).
    {
        const float4* zp = (const float4*)(z + (size_t)(tokbase + tok) * VQ_D + part * 16);
        float4 x0 = zp[0], x1 = zp[1], x2 = zp[2], x3 = zp[3];
        bf16x8 v0, v1;
        v0[0] = bf16rn(x0.x); v0[1] = bf16rn(x0.y); v0[2] = bf16rn(x0.z); v0[3] = bf16rn(x0.w);
        v0[4] = bf16rn(x1.x); v0[5] = bf16rn(x1.y); v0[6] = bf16rn(x1.z); v0[7] = bf16rn(x1.w);
        v1[0] = bf16rn(x2.x); v1[1] = bf16rn(x2.y); v1[2] = bf16rn(x2.z); v1[3] = bf16rn(x2.w);
        v1[4] = bf16rn(x3.x); v1[5] = bf16rn(x3.y); v1[6] = bf16rn(x3.z); v1[7] = bf16rn(x3.w);
        int t = tok >> 4, mrow = tok & 15, h = part >> 1, g0 = (part & 1) * 2;
        sA[(t * 2 + h) * 64 + (g0 * 16 + mrow)]       = v0;
        sA[(t * 2 + h) * 64 + ((g0 + 1) * 16 + mrow)] = v1;
    }
    __syncthreads();

    const int lane = tid & 63;
    const int wave = tid >> 6;          // k-split: wave w scans codes [w*256,(w+1)*256)
    const int m    = lane & 15;
    const int q    = lane >> 4;

    const bf16x8* cbb = (const bf16x8*)((const char*)ws + WS_CBB_BYTES);
    const float*  csq = ws + WS_CSQ;

    // Running argmin: low 4 mantissa bits of dist hold chunk index cc
    // (<=16 ulp perturbation — noise vs the 4e-5 bf16 rounding already accepted).
    float bestd[4][4];
    #pragma unroll
    for (int t = 0; t < 4; ++t)
        #pragma unroll
        for (int r = 0; r < 4; ++r) bestd[t][r] = 3.4e38f;

    for (int cc = 0; cc < 16; ++cc) {
        const int c = (wave << 4) | cc;
        bf16x8 b0 = cbb[(c * 2 + 0) * 64 + lane];   // L2-hot, contiguous 1 KB/wave
        bf16x8 b1 = cbb[(c * 2 + 1) * 64 + lane];
        float  cs = csq[(c << 4) + m];
        #pragma unroll
        for (int t = 0; t < 4; ++t) {
            bf16x8 a0 = sA[(t * 2 + 0) * 64 + lane];   // ds_read_b128, conflict-free
            bf16x8 a1 = sA[(t * 2 + 1) * 64 + lane];
            f32x4 acc = {0.f, 0.f, 0.f, 0.f};
            acc = __builtin_amdgcn_mfma_f32_16x16x32_bf16(a0, b0, acc, 0, 0, 0);
            acc = __builtin_amdgcn_mfma_f32_16x16x32_bf16(a1, b1, acc, 0, 0, 0);
            #pragma unroll
            for (int r = 0; r < 4; ++r) {              // C/D: col=m, row=q*4+r
                float dist = cs - 2.0f * acc[r];       // v_fma
                unsigned u = (__builtin_bit_cast(unsigned, dist) & ~15u) | (unsigned)cc;
                bestd[t][r] = fminf(bestd[t][r], __builtin_bit_cast(float, u));
            }
        }
    }

    // Cross-lane argmin over the 16 code-lanes; (v,k)-lexicographic preserves
    // the jnp first-min tie rule.
    #pragma unroll
    for (int t = 0; t < 4; ++t) {
        #pragma unroll
        for (int r = 0; r < 4; ++r) {
            float v = bestd[t][r];
            int   k = (wave << 8) | ((__builtin_bit_cast(unsigned, v) & 15u) << 4) | m;
            #pragma unroll
            for (int off = 1; off < 16; off <<= 1) {
                float v2 = __shfl_xor(v, off);
                int   k2 = __shfl_xor(k, off);
                if (v2 < v || (v2 == v && k2 < k)) { v = v2; k = k2; }
            }
            if (m == 0) {
                int tk = t * 16 + q * 4 + r;
                s_bv[wave][tk] = v; s_bk[wave][tk] = k;
            }
        }
    }
    __syncthreads();

    // Epilogue: combine 4 wave-chunks (ascending code ranges), exact fp32
    // gather + z_q write + loss partial.
    float bv = s_bv[0][tok]; int bk = s_bk[0][tok];
    #pragma unroll
    for (int w = 1; w < 4; ++w) {
        float v = s_bv[w][tok]; int k = s_bk[w][tok];
        if (v < bv || (v == bv && k < bk)) { bv = v; bk = k; }
    }
    const float4* crow = (const float4*)(cb + (size_t)bk * VQ_D + part * 16);
    const float4* zrow = (const float4*)(z + (size_t)(tokbase + tok) * VQ_D + part * 16);
    float4*       orow = (float4*)(out + (size_t)(tokbase + tok) * VQ_D + part * 16);
    float lsum = 0.f;
    #pragma unroll
    for (int j = 0; j < 4; ++j) {
        float4 cv = crow[j], zv = zrow[j];
        orow[j] = cv;
        float e0 = zv.x - cv.x, e1 = zv.y - cv.y;
        float e2 = zv.z - cv.z, e3 = zv.w - cv.w;
        lsum += e0 * e0 + e1 * e1 + e2 * e2 + e3 * e3;
    }
    #pragma unroll
    for (int off = 32; off > 0; off >>= 1) lsum += __shfl_down(lsum, off);
    if (lane == 0) s_loss[wave] = lsum;
    __syncthreads();

    // Last-block-done finalize (device-scope atomics; fence orders the loss add
    // before the counter add, and the counter read-modify-write synchronizes).
    if (tid == 0) {
        atomicAdd(ws + WS_LOSS, s_loss[0] + s_loss[1] + s_loss[2] + s_loss[3]);
        __threadfence();
        unsigned done = atomicAdd((unsigned*)ws + WS_CNT, 1u);
        if (done == VQ_NBLK - 1) {
            __threadfence();
            float total = __hip_atomic_load(ws + WS_LOSS, __ATOMIC_RELAXED,
                                            __HIP_MEMORY_SCOPE_AGENT);
            float msq = total * (1.0f / (float)VQ_NELEM);
            out[VQ_NELEM]     = msq;   // c_loss  (BETA = 1.0)
            out[VQ_NELEM + 1] = msq;   // cb_loss
        }
    }
}

extern "C" void kernel_launch(void* const* d_in, const int* in_sizes, int n_in,
                              void* d_out, int out_size, void* d_ws, size_t ws_size,
                              hipStream_t stream) {
    const float* z  = (const float*)d_in[0];
    const float* cb = (const float*)d_in[1];
    float* out = (float*)d_out;
    float* ws  = (float*)d_ws;

    vq_prep<<<dim3(32), dim3(256), 0, stream>>>(cb, ws);
    vq_main<<<dim3(VQ_NBLK), dim3(256), 0, stream>>>(z, cb, ws, out);
}

// Round 8
// 246.815 us; speedup vs baseline: 1.0314x; 1.0314x over previous
//
#include <hip/hip_runtime.h>

// VectorQuantizer: z [32,2048,64] f32, codebook [1024,64] f32.
// out = concat( z_q [4194304], c_loss [1], cb_loss [1] ); c_loss==cb_loss (BETA=1).
//
// R8: R7 spilled WITHOUT pins (VGPR=64, 500 MB scratch) -> root cause is the
// allocator's occupancy heuristic: it targets 8 waves/SIMD (<=64 VGPR) and
// spills rather than drop occupancy; __launch_bounds__'s 2nd arg is only a
// MINIMUM waves/EU (a VGPR cap), not a target. Fix: amdgpu_waves_per_eu(4,4)
// pins the target at 4 waves/EU -> 128-VGPR budget -> bestd + pipelined
// operands stay in registers. Compute design unchanged from R7 (verified):
// bf16 MFMA distance GEMM, LDS-staged A-frags, index-embedded v_min_f32
// argmin, exact fp32 gather/z_q/losses, last-block-done loss finalize.

#define VQ_NTOK   65536
#define VQ_D      64
#define VQ_K      1024
#define VQ_NELEM  (VQ_NTOK * VQ_D)
#define VQ_NBLK   (VQ_NTOK / 64)

typedef short bf16x8 __attribute__((ext_vector_type(8)));
typedef float f32x4  __attribute__((ext_vector_type(4)));

#define WS_CSQ       0        // 1024 floats: ||c_k||^2
#define WS_LOSS      1024     // 1 float: loss accumulator
#define WS_CNT       1025     // 1 uint: blocks-done counter
#define WS_CBB_BYTES 8192     // byte offset: 128 KB fragment-ordered bf16 codebook

__device__ __forceinline__ short bf16rn(float x) {   // round-to-nearest-even
    unsigned u = __builtin_bit_cast(unsigned, x);
    u += 0x7fffu + ((u >> 16) & 1u);
    return (short)(u >> 16);
}

// grid 32 x 256: zero accumulators + csq + bf16 fragment-ordered codebook.
// Fragment order: (chunk c, half h, lane L) -> cb[c*16+(L&15)][h*32+(L>>4)*8 ..+8)
__global__ __launch_bounds__(256) void vq_prep(const float* __restrict__ cb,
                                               float* __restrict__ ws) {
    int t = blockIdx.x * 256 + threadIdx.x;   // 0..8191
    if (t == 0) { ws[WS_LOSS] = 0.0f; ((unsigned*)ws)[WS_CNT] = 0u; }
    if (t < VQ_K) {
        const float4* row = (const float4*)(cb + t * VQ_D);
        float s = 0.f;
        #pragma unroll
        for (int j = 0; j < 16; ++j) {
            float4 c = row[j];
            s += c.x * c.x + c.y * c.y + c.z * c.z + c.w * c.w;
        }
        ws[WS_CSQ + t] = s;
    }
    int c = t >> 7, h = (t >> 6) & 1, L = t & 63;
    int k  = c * 16 + (L & 15);
    int d0 = h * 32 + ((L >> 4) << 3);
    const float4* p = (const float4*)(cb + k * VQ_D + d0);
    float4 x0 = p[0], x1 = p[1];
    bf16x8 v;
    v[0] = bf16rn(x0.x); v[1] = bf16rn(x0.y); v[2] = bf16rn(x0.z); v[3] = bf16rn(x0.w);
    v[4] = bf16rn(x1.x); v[5] = bf16rn(x1.y); v[6] = bf16rn(x1.z); v[7] = bf16rn(x1.w);
    bf16x8* cbb = (bf16x8*)((char*)ws + WS_CBB_BYTES);
    cbb[(c * 2 + h) * 64 + L] = v;
}

__global__ __launch_bounds__(256)
__attribute__((amdgpu_waves_per_eu(4, 4)))   // pin allocator target: 4 waves/EU -> 128 VGPR budget, no spill
void vq_main(
        const float* __restrict__ z, const float* __restrict__ cb,
        float* __restrict__ ws, float* __restrict__ out) {
    const int tid = threadIdx.x;
    const int bid = blockIdx.x;
    const int tokbase = bid << 6;
    const int tok = tid >> 2, part = tid & 3;   // token-quarter per thread

    __shared__ bf16x8 sA[512];          // 8 KB: 4 tiles x 2 halves x 64 lanes
    __shared__ float  s_bv[4][64];
    __shared__ int    s_bk[4][64];
    __shared__ float  s_loss[4];

    // Stage A-fragments into LDS (coalesced 64 B/thread z read, fragment-ordered).
    {
        const float4* zp = (const float4*)(z + (size_t)(tokbase + tok) * VQ_D + part * 16);
        float4 x0 = zp[0], x1 = zp[1], x2 = zp[2], x3 = zp[3];
        bf16x8 v0, v1;
        v0[0] = bf16rn(x0.x); v0[1] = bf16rn(x0.y); v0[2] = bf16rn(x0.z); v0[3] = bf16rn(x0.w);
        v0[4] = bf16rn(x1.x); v0[5] = bf16rn(x1.y); v0[6] = bf16rn(x1.z); v0[7] = bf16rn(x1.w);
        v1[0] = bf16rn(x2.x); v1[1] = bf16rn(x2.y); v1[2] = bf16rn(x2.z); v1[3] = bf16rn(x2.w);
        v1[4] = bf16rn(x3.x); v1[5] = bf16rn(x3.y); v1[6] = bf16rn(x3.z); v1[7] = bf16rn(x3.w);
        int t = tok >> 4, mrow = tok & 15, h = part >> 1, g0 = (part & 1) * 2;
        sA[(t * 2 + h) * 64 + (g0 * 16 + mrow)]       = v0;
        sA[(t * 2 + h) * 64 + ((g0 + 1) * 16 + mrow)] = v1;
    }
    __syncthreads();

    const int lane = tid & 63;
    const int wave = tid >> 6;          // k-split: wave w scans codes [w*256,(w+1)*256)
    const int m    = lane & 15;
    const int q    = lane >> 4;

    const bf16x8* cbb = (const bf16x8*)((const char*)ws + WS_CBB_BYTES);
    const float*  csq = ws + WS_CSQ;

    // Running argmin: low 4 mantissa bits of dist hold chunk index cc
    // (<=16 ulp perturbation — noise vs the 4e-5 bf16 rounding already accepted).
    float bestd[4][4];
    #pragma unroll
    for (int t = 0; t < 4; ++t)
        #pragma unroll
        for (int r = 0; r < 4; ++r) bestd[t][r] = 3.4e38f;

    for (int cc = 0; cc < 16; ++cc) {
        const int c = (wave << 4) | cc;
        bf16x8 b0 = cbb[(c * 2 + 0) * 64 + lane];   // L2-hot, contiguous 1 KB/wave
        bf16x8 b1 = cbb[(c * 2 + 1) * 64 + lane];
        float  cs = csq[(c << 4) + m];
        #pragma unroll
        for (int t = 0; t < 4; ++t) {
            bf16x8 a0 = sA[(t * 2 + 0) * 64 + lane];   // ds_read_b128, conflict-free
            bf16x8 a1 = sA[(t * 2 + 1) * 64 + lane];
            f32x4 acc = {0.f, 0.f, 0.f, 0.f};
            acc = __builtin_amdgcn_mfma_f32_16x16x32_bf16(a0, b0, acc, 0, 0, 0);
            acc = __builtin_amdgcn_mfma_f32_16x16x32_bf16(a1, b1, acc, 0, 0, 0);
            #pragma unroll
            for (int r = 0; r < 4; ++r) {              // C/D: col=m, row=q*4+r
                float dist = cs - 2.0f * acc[r];       // v_fma
                unsigned u = (__builtin_bit_cast(unsigned, dist) & ~15u) | (unsigned)cc;
                bestd[t][r] = fminf(bestd[t][r], __builtin_bit_cast(float, u));
            }
        }
    }

    // Cross-lane argmin over the 16 code-lanes; (v,k)-lexicographic preserves
    // the jnp first-min tie rule.
    #pragma unroll
    for (int t = 0; t < 4; ++t) {
        #pragma unroll
        for (int r = 0; r < 4; ++r) {
            float v = bestd[t][r];
            int   k = (wave << 8) | ((__builtin_bit_cast(unsigned, v) & 15u) << 4) | m;
            #pragma unroll
            for (int off = 1; off < 16; off <<= 1) {
                float v2 = __shfl_xor(v, off);
                int   k2 = __shfl_xor(k, off);
                if (v2 < v || (v2 == v && k2 < k)) { v = v2; k = k2; }
            }
            if (m == 0) {
                int tk = t * 16 + q * 4 + r;
                s_bv[wave][tk] = v; s_bk[wave][tk] = k;
            }
        }
    }
    __syncthreads();

    // Epilogue: combine 4 wave-chunks (ascending code ranges), exact fp32
    // gather + z_q write + loss partial.
    float bv = s_bv[0][tok]; int bk = s_bk[0][tok];
    #pragma unroll
    for (int w = 1; w < 4; ++w) {
        float v = s_bv[w][tok]; int k = s_bk[w][tok];
        if (v < bv || (v == bv && k < bk)) { bv = v; bk = k; }
    }
    const float4* crow = (const float4*)(cb + (size_t)bk * VQ_D + part * 16);
    const float4* zrow = (const float4*)(z + (size_t)(tokbase + tok) * VQ_D + part * 16);
    float4*       orow = (float4*)(out + (size_t)(tokbase + tok) * VQ_D + part * 16);
    float lsum = 0.f;
    #pragma unroll
    for (int j = 0; j < 4; ++j) {
        float4 cv = crow[j], zv = zrow[j];
        orow[j] = cv;
        float e0 = zv.x - cv.x, e1 = zv.y - cv.y;
        float e2 = zv.z - cv.z, e3 = zv.w - cv.w;
        lsum += e0 * e0 + e1 * e1 + e2 * e2 + e3 * e3;
    }
    #pragma unroll
    for (int off = 32; off > 0; off >>= 1) lsum += __shfl_down(lsum, off);
    if (lane == 0) s_loss[wave] = lsum;
    __syncthreads();

    // Last-block-done finalize (device-scope atomics; fence orders the loss add
    // before the counter add).
    if (tid == 0) {
        atomicAdd(ws + WS_LOSS, s_loss[0] + s_loss[1] + s_loss[2] + s_loss[3]);
        __threadfence();
        unsigned done = atomicAdd((unsigned*)ws + WS_CNT, 1u);
        if (done == VQ_NBLK - 1) {
            __threadfence();
            float total = __hip_atomic_load(ws + WS_LOSS, __ATOMIC_RELAXED,
                                            __HIP_MEMORY_SCOPE_AGENT);
            float msq = total * (1.0f / (float)VQ_NELEM);
            out[VQ_NELEM]     = msq;   // c_loss  (BETA = 1.0)
            out[VQ_NELEM + 1] = msq;   // cb_loss
        }
    }
}

extern "C" void kernel_launch(void* const* d_in, const int* in_sizes, int n_in,
                              void* d_out, int out_size, void* d_ws, size_t ws_size,
                              hipStream_t stream) {
    const float* z  = (const float*)d_in[0];
    const float* cb = (const float*)d_in[1];
    float* out = (float*)d_out;
    float* ws  = (float*)d_ws;

    vq_prep<<<dim3(32), dim3(256), 0, stream>>>(cb, ws);
    vq_main<<<dim3(VQ_NBLK), dim3(256), 0, stream>>>(z, cb, ws, out);
}

// Round 9
// 142.705 us; speedup vs baseline: 1.7839x; 1.7296x over previous
//
#include <hip/hip_runtime.h>

// VectorQuantizer: z [32,2048,64] f32, codebook [1024,64] f32.
// out = concat( z_q [4194304], c_loss [1], cb_loss [1] ); c_loss==cb_loss (BETA=1).
//
// R9: R7/R8 spilled because the k-split design needs >64 live VGPRs once the
// unroller pipelines B-operands, and the allocator refuses to budget >64
// (launch_bounds/waves_per_eu both ignored). Redesign to fit 64 by construction:
// wave owns 16 tokens (A-frag = 8 VGPRs) and scans ALL 1024 codes in 64 chunks
// (live: A 8 + B 8 + acc 4 + bestd 4 + addr ~15 = ~45 VGPR). No LDS staging,
// no cross-wave combine. B stream = 128 KB L2-resident cbb shared by all waves.
// bf16 MFMA distance GEMM; index-embedded v_min_f32 argmin; exact fp32
// gather / z_q / losses; last-block-done loss finalize.

#define VQ_NTOK   65536
#define VQ_D      64
#define VQ_K      1024
#define VQ_NELEM  (VQ_NTOK * VQ_D)
#define VQ_NBLK   (VQ_NTOK / 64)

typedef short bf16x8 __attribute__((ext_vector_type(8)));
typedef float f32x4  __attribute__((ext_vector_type(4)));

#define WS_CSQ       0        // 1024 floats: ||c_k||^2
#define WS_LOSS      1024     // 1 float: loss accumulator
#define WS_CNT       1025     // 1 uint: blocks-done counter
#define WS_CBB_BYTES 8192     // byte offset: 128 KB fragment-ordered bf16 codebook

__device__ __forceinline__ short bf16rn(float x) {   // round-to-nearest-even
    unsigned u = __builtin_bit_cast(unsigned, x);
    u += 0x7fffu + ((u >> 16) & 1u);
    return (short)(u >> 16);
}

// grid 32 x 256: zero accumulators + csq + bf16 fragment-ordered codebook.
// Fragment order: (chunk c, half h, lane L) -> cb[c*16+(L&15)][h*32+(L>>4)*8 ..+8)
__global__ __launch_bounds__(256) void vq_prep(const float* __restrict__ cb,
                                               float* __restrict__ ws) {
    int t = blockIdx.x * 256 + threadIdx.x;   // 0..8191
    if (t == 0) { ws[WS_LOSS] = 0.0f; ((unsigned*)ws)[WS_CNT] = 0u; }
    if (t < VQ_K) {
        const float4* row = (const float4*)(cb + t * VQ_D);
        float s = 0.f;
        #pragma unroll
        for (int j = 0; j < 16; ++j) {
            float4 c = row[j];
            s += c.x * c.x + c.y * c.y + c.z * c.z + c.w * c.w;
        }
        ws[WS_CSQ + t] = s;
    }
    int c = t >> 7, h = (t >> 6) & 1, L = t & 63;
    int k  = c * 16 + (L & 15);
    int d0 = h * 32 + ((L >> 4) << 3);
    const float4* p = (const float4*)(cb + k * VQ_D + d0);
    float4 x0 = p[0], x1 = p[1];
    bf16x8 v;
    v[0] = bf16rn(x0.x); v[1] = bf16rn(x0.y); v[2] = bf16rn(x0.z); v[3] = bf16rn(x0.w);
    v[4] = bf16rn(x1.x); v[5] = bf16rn(x1.y); v[6] = bf16rn(x1.z); v[7] = bf16rn(x1.w);
    bf16x8* cbb = (bf16x8*)((char*)ws + WS_CBB_BYTES);
    cbb[(c * 2 + h) * 64 + L] = v;
}

__global__ __launch_bounds__(256) void vq_main(
        const float* __restrict__ z, const float* __restrict__ cb,
        float* __restrict__ ws, float* __restrict__ out) {
    const int tid = threadIdx.x;
    const int bid = blockIdx.x;
    const int tokbase = bid << 6;
    const int lane = tid & 63;
    const int wave = tid >> 6;          // wave owns tokens [wave*16, wave*16+16)
    const int m    = lane & 15;
    const int q    = lane >> 4;

    __shared__ float s_bv[64];
    __shared__ int   s_bk[64];
    __shared__ float s_loss[4];

    // A fragment for this wave's 16-token tile: A[m][k=q*8+j], two K-halves.
    bf16x8 a0, a1;
    {
        const float* rowp = z + (size_t)(tokbase + wave * 16 + m) * VQ_D + (q << 3);
        const float4* p0 = (const float4*)(rowp);
        const float4* p1 = (const float4*)(rowp + 32);
        float4 x0 = p0[0], x1 = p0[1], x2 = p1[0], x3 = p1[1];
        a0[0] = bf16rn(x0.x); a0[1] = bf16rn(x0.y); a0[2] = bf16rn(x0.z); a0[3] = bf16rn(x0.w);
        a0[4] = bf16rn(x1.x); a0[5] = bf16rn(x1.y); a0[6] = bf16rn(x1.z); a0[7] = bf16rn(x1.w);
        a1[0] = bf16rn(x2.x); a1[1] = bf16rn(x2.y); a1[2] = bf16rn(x2.z); a1[3] = bf16rn(x2.w);
        a1[4] = bf16rn(x3.x); a1[5] = bf16rn(x3.y); a1[6] = bf16rn(x3.z); a1[7] = bf16rn(x3.w);
    }

    const bf16x8* cbb = (const bf16x8*)((const char*)ws + WS_CBB_BYTES);
    const float*  csq = ws + WS_CSQ;

    // Running argmin: low 6 mantissa bits of dist hold chunk index c
    // (64-ulp, ~8e-6 relative — noise vs the 4e-5 bf16 rounding already accepted).
    float bestd[4];
    #pragma unroll
    for (int r = 0; r < 4; ++r) bestd[r] = 3.4e38f;

    #pragma clang loop unroll_count(2)
    for (int c = 0; c < 64; ++c) {
        bf16x8 b0 = cbb[(c * 2 + 0) * 64 + lane];   // 128 KB L2-resident stream,
        bf16x8 b1 = cbb[(c * 2 + 1) * 64 + lane];   // shared by all waves (L1-hot)
        float  cs = csq[(c << 4) + m];
        f32x4 acc = {0.f, 0.f, 0.f, 0.f};
        acc = __builtin_amdgcn_mfma_f32_16x16x32_bf16(a0, b0, acc, 0, 0, 0);
        acc = __builtin_amdgcn_mfma_f32_16x16x32_bf16(a1, b1, acc, 0, 0, 0);
        #pragma unroll
        for (int r = 0; r < 4; ++r) {               // C/D: col=m (code), row=q*4+r (token)
            float dist = cs - 2.0f * acc[r];        // v_fma
            unsigned u = (__builtin_bit_cast(unsigned, dist) & ~63u) | (unsigned)c;
            bestd[r] = fminf(bestd[r], __builtin_bit_cast(float, u));
        }
    }

    // Cross-lane argmin over the 16 code-lanes (same token-row, m = 0..15);
    // (v,k)-lexicographic preserves the jnp first-min tie rule.
    #pragma unroll
    for (int r = 0; r < 4; ++r) {
        float v = bestd[r];
        int   k = (int)((__builtin_bit_cast(unsigned, v) & 63u) << 4) | m;
        #pragma unroll
        for (int off = 1; off < 16; off <<= 1) {
            float v2 = __shfl_xor(v, off);
            int   k2 = __shfl_xor(k, off);
            if (v2 < v || (v2 == v && k2 < k)) { v = v2; k = k2; }
        }
        if (m == 0) {
            s_bv[wave * 16 + q * 4 + r] = v;
            s_bk[wave * 16 + q * 4 + r] = k;
        }
    }
    __syncthreads();

    // Epilogue: thread -> (token, quarter-row); exact fp32 gather + z_q + loss.
    const int tok = tid >> 2, part = tid & 3;
    const int bk = s_bk[tok];
    const float4* crow = (const float4*)(cb + (size_t)bk * VQ_D + part * 16);
    const float4* zrow = (const float4*)(z + (size_t)(tokbase + tok) * VQ_D + part * 16);
    float4*       orow = (float4*)(out + (size_t)(tokbase + tok) * VQ_D + part * 16);
    float lsum = 0.f;
    #pragma unroll
    for (int j = 0; j < 4; ++j) {
        float4 cv = crow[j], zv = zrow[j];
        orow[j] = cv;
        float e0 = zv.x - cv.x, e1 = zv.y - cv.y;
        float e2 = zv.z - cv.z, e3 = zv.w - cv.w;
        lsum += e0 * e0 + e1 * e1 + e2 * e2 + e3 * e3;
    }
    #pragma unroll
    for (int off = 32; off > 0; off >>= 1) lsum += __shfl_down(lsum, off);
    if (lane == 0) s_loss[wave] = lsum;
    __syncthreads();

    // Last-block-done finalize (device-scope atomics; fence orders the loss add
    // before the counter add).
    if (tid == 0) {
        atomicAdd(ws + WS_LOSS, s_loss[0] + s_loss[1] + s_loss[2] + s_loss[3]);
        __threadfence();
        unsigned done = atomicAdd((unsigned*)ws + WS_CNT, 1u);
        if (done == VQ_NBLK - 1) {
            __threadfence();
            float total = __hip_atomic_load(ws + WS_LOSS, __ATOMIC_RELAXED,
                                            __HIP_MEMORY_SCOPE_AGENT);
            float msq = total * (1.0f / (float)VQ_NELEM);
            out[VQ_NELEM]     = msq;   // c_loss  (BETA = 1.0)
            out[VQ_NELEM + 1] = msq;   // cb_loss
        }
    }
}

extern "C" void kernel_launch(void* const* d_in, const int* in_sizes, int n_in,
                              void* d_out, int out_size, void* d_ws, size_t ws_size,
                              hipStream_t stream) {
    const float* z  = (const float*)d_in[0];
    const float* cb = (const float*)d_in[1];
    float* out = (float*)d_out;
    float* ws  = (float*)d_ws;

    vq_prep<<<dim3(32), dim3(256), 0, stream>>>(cb, ws);
    vq_main<<<dim3(VQ_NBLK), dim3(256), 0, stream>>>(z, cb, ws, out);
}